// Round 11
// baseline (267.315 us; speedup 1.0000x reference)
//
#include <hip/hip_runtime.h>
#include <stdint.h>

// ---------------------------------------------------------------------------
// HistoryEmbTable: emb.at[push_idx].set(x) then gather emb[pull_idx].
// Last push (highest i) wins on duplicate push indices.
//
// Partition pipeline (rounds 7-11):
//   bucket = key>>17 (512 buckets, 512KB emb window each)
//   K1: FUSED LDS-staged 512-bin scatter (round-11): first gp blocks bin
//       push_idx chunks, remaining blocks bin pull_idx chunks -- the two
//       independent scatters now run CONCURRENTLY instead of back-to-back.
//       Both sides emit u64 (key<<32 | original_index) runs. LDS-atomic
//       ranking, bin-contiguous copy-out, ~512 global cursor atomics/block.
//   K2: per-bucket exact last-write-wins hash in LDS (16K x u64 = 128KB) +
//       16KB bloom of pushed keys (round-10: kills the dependent LDS walk
//       for ~87.7% of pulls). MBLK=1024 (round-8: 128KB table -> 1 WG/CU,
//       so waves must come from block size; round-9 showed trading waves
//       for batch regresses). Round-11: match writes out[j] DIRECTLY
//       (j carried in the pull run) -- staging/dest/unpermute eliminated.
// Winner = max push pos (order-free); each pull j is written exactly once,
// so output is deterministic despite nondeterministic scatter order.
// ---------------------------------------------------------------------------

typedef unsigned long long u64;
typedef unsigned u32;

#define NB     512              // buckets
#define BSHIFT 17               // bucket = key >> 17 (keys < 2^26)
#define BLK    256
#define MBLK   1024             // match block: 16 waves
#define MB     4                // match batch (items/thread/iter)
#define VPT    16
#define CHUNK  (BLK * VPT)      // 4096 items per scatter block
#define CAP    12288            // per-bucket run capacity (mean 7812, +50 sigma)
#define CPAD   16               // ints per cursor (64B line)
#define LSLOTS 16384            // LDS hash slots (128KB)
#define LMASK  (LSLOTS - 1)
#define BBITS  131072           // bloom bits (2^17) = 16KB
#define BWORDS (BBITS / 32)
#define BMASK  (BBITS - 1)

__device__ __forceinline__ u32 hkey(int key) { return (u32)key * 2654435761u; }

// ---- K1: fused LDS-binned scatter into 512 bucket runs (push + pull) ----
__global__ __launch_bounds__(BLK)
void scatter_kernel(const int* __restrict__ push_idx, int n_push, int gp,
                    const int* __restrict__ pull_idx, int n_pull,
                    int* __restrict__ cur_push, int* __restrict__ cur_pull,
                    u64* __restrict__ push_runs, u64* __restrict__ pull_runs) {
    const bool is_push = (int)blockIdx.x < gp;
    const int* __restrict__ idx = is_push ? push_idx : pull_idx;
    const int n   = is_push ? n_push : n_pull;
    const int cid = is_push ? blockIdx.x : blockIdx.x - gp;
    int* __restrict__ cursors = is_push ? cur_push : cur_pull;
    u64* __restrict__ runs    = is_push ? push_runs : pull_runs;

    __shared__ u64 buf[CHUNK];          // 32KB
    __shared__ int cnt[NB];             // 2KB
    __shared__ int basel[NB];           // 2KB
    __shared__ int baseg[NB];           // 2KB
    __shared__ int scan[NB];            // 2KB
    int t = threadIdx.x;
    for (int b = t; b < NB; b += BLK) cnt[b] = 0;
    __syncthreads();

    int base = cid * CHUNK;
    int   key_r[VPT];
    short bin_r[VPT];                   // < 512
    short pos_r[VPT];                   // < 4096
    #pragma unroll
    for (int e = 0; e < VPT; ++e) {
        int i = base + e * BLK + t;     // coalesced index load
        if (i < n) {
            int key = idx[i];
            int b = key >> BSHIFT;
            key_r[e] = key;
            bin_r[e] = (short)b;
            pos_r[e] = (short)atomicAdd(&cnt[b], 1);   // LDS atomic (cheap)
        } else bin_r[e] = -1;
    }
    __syncthreads();

    // exclusive scan of cnt -> basel (Hillis-Steele, 2 elems/thread)
    scan[t] = cnt[t]; scan[t + BLK] = cnt[t + BLK];
    __syncthreads();
    for (int d = 1; d < NB; d <<= 1) {
        int a0 = (t       >= d) ? scan[t       - d] : 0;
        int a1 = (t + BLK >= d) ? scan[t + BLK - d] : 0;
        __syncthreads();
        scan[t] += a0; scan[t + BLK] += a1;
        __syncthreads();
    }
    basel[t]       = scan[t]       - cnt[t];
    basel[t + BLK] = scan[t + BLK] - cnt[t + BLK];
    __syncthreads();

    // reserve global run space: ~512 global atomics per block (not 4096)
    for (int b = t; b < NB; b += BLK)
        if (cnt[b] > 0) baseg[b] = atomicAdd(&cursors[b * CPAD], cnt[b]);

    // stage items into LDS, bin-grouped
    #pragma unroll
    for (int e = 0; e < VPT; ++e) {
        if (bin_r[e] >= 0) {
            int i = base + e * BLK + t;
            buf[basel[bin_r[e]] + pos_r[e]] =
                ((u64)(u32)key_r[e] << 32) | (u32)i;    // key | original index
        }
    }
    __syncthreads();

    // copy out: consecutive threads -> consecutive buf slots -> bin-contiguous
    int total = scan[NB - 1];
    for (int q = t; q < total; q += BLK) {
        u64 packed = buf[q];
        int key = (int)(packed >> 32);
        int b = key >> BSHIFT;
        int r = baseg[b] + (q - basel[b]);
        if (r < CAP)                                    // overflow guard (P~0)
            runs[(size_t)b * CAP + r] = packed;
    }
}

// ---- K2: per-bucket LDS-exact match (+bloom), direct out[j] write ----
__global__ __launch_bounds__(MBLK)
void match_kernel(const u64* __restrict__ push_runs,
                  const u64* __restrict__ pull_runs,
                  const int* __restrict__ cur_push,
                  const int* __restrict__ cur_pull,
                  const float* __restrict__ x,
                  const float* __restrict__ emb,
                  float* __restrict__ out) {
    __shared__ u64 tbl[LSLOTS];     // 128KB
    __shared__ u32 bloom[BWORDS];   // 16KB  (total 144KB -> still 1 WG/CU)
    int b = blockIdx.x;
    int np = cur_push[b * CPAD]; np = np < CAP ? np : CAP;
    int nl = cur_pull[b * CPAD]; nl = nl < CAP ? nl : CAP;
    for (int i = threadIdx.x; i < LSLOTS; i += MBLK) tbl[i] = 0ull;
    for (int i = threadIdx.x; i < BWORDS; i += MBLK) bloom[i] = 0u;
    __syncthreads();

    // build: bloom bit + exact last-write-wins hash (LDS atomics)
    const u64* prun = push_runs + (size_t)b * CAP;
    for (int i = threadIdx.x; i < np; i += MBLK) {
        u64 packed = prun[i];
        int key = (int)(packed >> 32);
        u32 h = hkey(key);
        atomicOr(&bloom[(h & BMASK) >> 5], 1u << (h & 31));
        u32 key1 = (u32)key + 1u;
        u64 want = ((u64)key1 << 32) | ((u32)packed + 1u);   // (key+1)|(pos+1)
        u32 s = (h >> 18) & LMASK;
        for (;;) {
            u64 prev = atomicCAS(&tbl[s], 0ull, want);
            if (prev == 0ull) break;                          // claimed
            if ((prev >> 32) == key1) { atomicMax(&tbl[s], want); break; }
            s = (s + 1) & LMASK;
        }
    }
    __syncthreads();

    // probe pulls, batch-4 (2x ulonglong2 coalesced run loads); emb loads in
    // flight first; bloom kills the walk for ~87.7% of pulls; out[j] direct.
    const u64* lrun = pull_runs + (size_t)b * CAP;
    const int STRIDE = MBLK * MB;                 // 4096
    for (int i = threadIdx.x * MB; i + MB <= nl; i += STRIDE) {
        ulonglong2 e0 = *(const ulonglong2*)(lrun + i);
        ulonglong2 e1 = *(const ulonglong2*)(lrun + i + 2);
        u64 ent[MB] = {e0.x, e0.y, e1.x, e1.y};
        int k[MB];
        #pragma unroll
        for (int e = 0; e < MB; ++e) k[e] = (int)(ent[e] >> 32);
        float g[MB];
        #pragma unroll
        for (int e = 0; e < MB; ++e) g[e] = emb[k[e]];        // 4 in flight
        u32 h[MB], bw[MB];
        #pragma unroll
        for (int e = 0; e < MB; ++e) h[e] = hkey(k[e]);
        #pragma unroll
        for (int e = 0; e < MB; ++e) bw[e] = bloom[(h[e] & BMASK) >> 5];
        #pragma unroll
        for (int e = 0; e < MB; ++e) {
            float v = g[e];
            if ((bw[e] >> (h[e] & 31)) & 1u) {                // maybe pushed
                u32 key1 = (u32)k[e] + 1u;
                u32 s = (h[e] >> 18) & LMASK;
                for (;;) {
                    u64 cur = tbl[s];
                    if (cur == 0ull) break;                   // bloom FP
                    if ((cur >> 32) == key1) { v = x[(u32)cur - 1u]; break; }
                    s = (s + 1) & LMASK;
                }
            }
            out[(u32)ent[e]] = v;                             // scattered 4B (L3)
        }
    }
    // tail (< MB items at the end)
    int tail = (nl / MB) * MB;
    for (int i = tail + threadIdx.x; i < nl; i += MBLK) {
        u64 ent = lrun[i];
        int key = (int)(ent >> 32);
        float v = emb[key];
        u32 h = hkey(key);
        if ((bloom[(h & BMASK) >> 5] >> (h & 31)) & 1u) {
            u32 key1 = (u32)key + 1u;
            u32 s = (h >> 18) & LMASK;
            for (;;) {
                u64 cur = tbl[s];
                if (cur == 0ull) break;
                if ((cur >> 32) == key1) { v = x[(u32)cur - 1u]; break; }
                s = (s + 1) & LMASK;
            }
        }
        out[(u32)ent] = v;
    }
}

extern "C" void kernel_launch(void* const* d_in, const int* in_sizes, int n_in,
                              void* d_out, int out_size, void* d_ws, size_t ws_size,
                              hipStream_t stream) {
    const float* emb      = (const float*)d_in[0];
    const float* x        = (const float*)d_in[1];
    const int*   push_idx = (const int*)d_in[2];
    const int*   pull_idx = (const int*)d_in[3];
    float* out = (float*)d_out;

    const int n_push = in_sizes[2];
    const int n_pull = in_sizes[3];

    // ws layout: [cur_push][cur_pull] (zeroed) [push_runs][pull_runs]
    char* p = (char*)d_ws;
    int* cur_push = (int*)p;                  p += (size_t)NB * CPAD * 4;
    int* cur_pull = (int*)p;                  p += (size_t)NB * CPAD * 4;
    size_t zero_bytes = (size_t)(p - (char*)d_ws);
    u64* push_runs = (u64*)p;                 p += (size_t)NB * CAP * 8;
    u64* pull_runs = (u64*)p;                 p += (size_t)NB * CAP * 8;

    hipMemsetAsync(d_ws, 0, zero_bytes, stream);   // 128KB only

    int gp = (n_push + CHUNK - 1) / CHUNK;
    int gl = (n_pull + CHUNK - 1) / CHUNK;
    scatter_kernel<<<gp + gl, BLK, 0, stream>>>(
        push_idx, n_push, gp, pull_idx, n_pull,
        cur_push, cur_pull, push_runs, pull_runs);
    match_kernel<<<NB, MBLK, 0, stream>>>(push_runs, pull_runs,
                                          cur_push, cur_pull, x, emb, out);
}

// Round 12
// 227.388 us; speedup vs baseline: 1.1756x; 1.1756x over previous
//
#include <hip/hip_runtime.h>
#include <stdint.h>

// ---------------------------------------------------------------------------
// HistoryEmbTable: emb.at[push_idx].set(x) then gather emb[pull_idx].
// Last push (highest i) wins on duplicate push indices.
//
// Partition pipeline (best-of rounds 7-11):
//   bucket = key>>17 (512 buckets, 512KB emb window each)
//   K1: FUSED LDS-staged 512-bin scatter (round-11 win): first gp blocks bin
//       push_idx chunks -> u64 (key|pos) runs; remaining blocks bin pull_idx
//       chunks -> int key runs + dest[j]=slot. LDS-atomic ranking,
//       bin-contiguous copy-out, ~512 global cursor atomics/block.
//   K2: per-bucket exact last-write-wins hash in LDS (16K x u64 = 128KB) +
//       16KB bloom of pushed keys (round-10 win: kills the dependent LDS
//       walk for ~87.7% of pulls). MBLK=1024 (round-8: 128KB -> 1 WG/CU, so
//       waves come from block size). COALESCED staging write -- round-11
//       showed scattered 4B writes into an L3-pressured region cost +95us
//       (WRITE_SIZE 16->134MB); scattered reads are fine, scattered writes
//       are not. batch-4 emb loads in flight (chain-break).
//   K3: unpermute out[j] = staging[dest[j]] (coalesced read dest, L3-served
//       staging gather, coalesced out write).
// Winner = max push pos (order-free); each j reads its own staging slot, so
// output is deterministic despite nondeterministic scatter order.
// ---------------------------------------------------------------------------

typedef unsigned long long u64;
typedef unsigned u32;

#define NB     512              // buckets
#define BSHIFT 17               // bucket = key >> 17 (keys < 2^26)
#define BLK    256
#define MBLK   1024             // match block: 16 waves
#define MB     4                // match batch (items/thread/iter)
#define VPT    16
#define CHUNK  (BLK * VPT)      // 4096 items per scatter block
#define CAP    12288            // per-bucket run capacity (mean 7812, +50 sigma)
#define CPAD   16               // ints per cursor (64B line)
#define LSLOTS 16384            // LDS hash slots (128KB)
#define LMASK  (LSLOTS - 1)
#define BBITS  131072           // bloom bits (2^17) = 16KB
#define BWORDS (BBITS / 32)
#define BMASK  (BBITS - 1)

__device__ __forceinline__ u32 hkey(int key) { return (u32)key * 2654435761u; }

// ---- K1: fused LDS-binned scatter into 512 bucket runs (push + pull) ----
__global__ __launch_bounds__(BLK)
void scatter_kernel(const int* __restrict__ push_idx, int n_push, int gp,
                    const int* __restrict__ pull_idx, int n_pull,
                    int* __restrict__ cur_push, int* __restrict__ cur_pull,
                    u64* __restrict__ push_runs,
                    int* __restrict__ pull_keys, int* __restrict__ dest) {
    const bool is_push = (int)blockIdx.x < gp;
    const int* __restrict__ idx = is_push ? push_idx : pull_idx;
    const int n   = is_push ? n_push : n_pull;
    const int cid = is_push ? blockIdx.x : blockIdx.x - gp;
    int* __restrict__ cursors = is_push ? cur_push : cur_pull;

    __shared__ u64 buf[CHUNK];          // 32KB
    __shared__ int cnt[NB];             // 2KB
    __shared__ int basel[NB];           // 2KB
    __shared__ int baseg[NB];           // 2KB
    __shared__ int scan[NB];            // 2KB
    int t = threadIdx.x;
    for (int b = t; b < NB; b += BLK) cnt[b] = 0;
    __syncthreads();

    int base = cid * CHUNK;
    int   key_r[VPT];
    short bin_r[VPT];                   // < 512
    short pos_r[VPT];                   // < 4096
    #pragma unroll
    for (int e = 0; e < VPT; ++e) {
        int i = base + e * BLK + t;     // coalesced index load
        if (i < n) {
            int key = idx[i];
            int b = key >> BSHIFT;
            key_r[e] = key;
            bin_r[e] = (short)b;
            pos_r[e] = (short)atomicAdd(&cnt[b], 1);   // LDS atomic (cheap)
        } else bin_r[e] = -1;
    }
    __syncthreads();

    // exclusive scan of cnt -> basel (Hillis-Steele, 2 elems/thread)
    scan[t] = cnt[t]; scan[t + BLK] = cnt[t + BLK];
    __syncthreads();
    for (int d = 1; d < NB; d <<= 1) {
        int a0 = (t       >= d) ? scan[t       - d] : 0;
        int a1 = (t + BLK >= d) ? scan[t + BLK - d] : 0;
        __syncthreads();
        scan[t] += a0; scan[t + BLK] += a1;
        __syncthreads();
    }
    basel[t]       = scan[t]       - cnt[t];
    basel[t + BLK] = scan[t + BLK] - cnt[t + BLK];
    __syncthreads();

    // reserve global run space: ~512 global atomics per block (not 4096)
    for (int b = t; b < NB; b += BLK)
        if (cnt[b] > 0) baseg[b] = atomicAdd(&cursors[b * CPAD], cnt[b]);

    // stage items into LDS, bin-grouped
    #pragma unroll
    for (int e = 0; e < VPT; ++e) {
        if (bin_r[e] >= 0) {
            int i = base + e * BLK + t;
            buf[basel[bin_r[e]] + pos_r[e]] =
                ((u64)(u32)key_r[e] << 32) | (u32)i;    // key | original index
        }
    }
    __syncthreads();

    // copy out: consecutive threads -> consecutive buf slots -> bin-contiguous
    int total = scan[NB - 1];
    for (int q = t; q < total; q += BLK) {
        u64 packed = buf[q];
        int key = (int)(packed >> 32);
        int b = key >> BSHIFT;
        int r = baseg[b] + (q - basel[b]);
        if (r < CAP) {                                  // overflow guard (P~0)
            int gpos = b * CAP + r;
            if (is_push) {
                push_runs[gpos] = packed;               // key | push pos
            } else {
                pull_keys[gpos] = key;
                dest[(u32)packed] = gpos;               // dest[j] = staging slot
            }
        }
    }
}

// ---- K2: per-bucket LDS-exact match (+bloom) -> coalesced staging ----
__global__ __launch_bounds__(MBLK)
void match_kernel(const u64* __restrict__ push_runs,
                  const int* __restrict__ pull_keys,
                  const int* __restrict__ cur_push,
                  const int* __restrict__ cur_pull,
                  const float* __restrict__ x,
                  const float* __restrict__ emb,
                  float* __restrict__ staging) {
    __shared__ u64 tbl[LSLOTS];     // 128KB
    __shared__ u32 bloom[BWORDS];   // 16KB  (total 144KB -> still 1 WG/CU)
    int b = blockIdx.x;
    int np = cur_push[b * CPAD]; np = np < CAP ? np : CAP;
    int nl = cur_pull[b * CPAD]; nl = nl < CAP ? nl : CAP;
    for (int i = threadIdx.x; i < LSLOTS; i += MBLK) tbl[i] = 0ull;
    for (int i = threadIdx.x; i < BWORDS; i += MBLK) bloom[i] = 0u;
    __syncthreads();

    // build: bloom bit + exact last-write-wins hash (LDS atomics)
    const u64* prun = push_runs + (size_t)b * CAP;
    for (int i = threadIdx.x; i < np; i += MBLK) {
        u64 packed = prun[i];
        int key = (int)(packed >> 32);
        u32 h = hkey(key);
        atomicOr(&bloom[(h & BMASK) >> 5], 1u << (h & 31));
        u32 key1 = (u32)key + 1u;
        u64 want = ((u64)key1 << 32) | ((u32)packed + 1u);   // (key+1)|(pos+1)
        u32 s = (h >> 18) & LMASK;
        for (;;) {
            u64 prev = atomicCAS(&tbl[s], 0ull, want);
            if (prev == 0ull) break;                          // claimed
            if ((prev >> 32) == key1) { atomicMax(&tbl[s], want); break; }
            s = (s + 1) & LMASK;
        }
    }
    __syncthreads();

    // probe pulls, batch-4: emb loads in flight; bloom kills the walk for
    // ~87.7% of pulls; coalesced float4 staging store.
    const int* lkeys = pull_keys + (size_t)b * CAP;
    float* stg = staging + (size_t)b * CAP;
    const int STRIDE = MBLK * MB;                 // 4096
    for (int i = threadIdx.x * MB; i + MB <= nl; i += STRIDE) {
        int4 kk = *(const int4*)(lkeys + i);
        int k[MB] = {kk.x, kk.y, kk.z, kk.w};
        float g[MB];
        #pragma unroll
        for (int e = 0; e < MB; ++e) g[e] = emb[k[e]];        // 4 in flight
        u32 h[MB], bw[MB];
        #pragma unroll
        for (int e = 0; e < MB; ++e) h[e] = hkey(k[e]);
        #pragma unroll
        for (int e = 0; e < MB; ++e) bw[e] = bloom[(h[e] & BMASK) >> 5];
        float r[MB];
        #pragma unroll
        for (int e = 0; e < MB; ++e) {
            float v = g[e];
            if ((bw[e] >> (h[e] & 31)) & 1u) {                // maybe pushed
                u32 key1 = (u32)k[e] + 1u;
                u32 s = (h[e] >> 18) & LMASK;
                for (;;) {
                    u64 cur = tbl[s];
                    if (cur == 0ull) break;                   // bloom FP
                    if ((cur >> 32) == key1) { v = x[(u32)cur - 1u]; break; }
                    s = (s + 1) & LMASK;
                }
            }
            r[e] = v;
        }
        *(float4*)(stg + i) = make_float4(r[0], r[1], r[2], r[3]);
    }
    // tail (< MB items at the end)
    int tail = (nl / MB) * MB;
    for (int i = tail + threadIdx.x; i < nl; i += MBLK) {
        int key = lkeys[i];
        float v = emb[key];
        u32 h = hkey(key);
        if ((bloom[(h & BMASK) >> 5] >> (h & 31)) & 1u) {
            u32 key1 = (u32)key + 1u;
            u32 s = (h >> 18) & LMASK;
            for (;;) {
                u64 cur = tbl[s];
                if (cur == 0ull) break;
                if ((cur >> 32) == key1) { v = x[(u32)cur - 1u]; break; }
                s = (s + 1) & LMASK;
            }
        }
        stg[i] = v;
    }
}

// ---- K3: unpermute (coalesced dest read, L3 staging gather, coalesced out) ----
__global__ __launch_bounds__(BLK)
void unpermute_kernel(const int* __restrict__ dest,
                      const float* __restrict__ staging,
                      float* __restrict__ out, int n) {
    int j0 = (blockIdx.x * BLK + threadIdx.x) * 4;
    if (j0 + 4 <= n) {
        int4 d = *(const int4*)(dest + j0);
        *(float4*)(out + j0) =
            make_float4(staging[d.x], staging[d.y], staging[d.z], staging[d.w]);
    } else {
        for (int j = j0; j < n; ++j) out[j] = staging[dest[j]];
    }
}

extern "C" void kernel_launch(void* const* d_in, const int* in_sizes, int n_in,
                              void* d_out, int out_size, void* d_ws, size_t ws_size,
                              hipStream_t stream) {
    const float* emb      = (const float*)d_in[0];
    const float* x        = (const float*)d_in[1];
    const int*   push_idx = (const int*)d_in[2];
    const int*   pull_idx = (const int*)d_in[3];
    float* out = (float*)d_out;

    const int n_push = in_sizes[2];
    const int n_pull = in_sizes[3];

    // ws layout: [cur_push][cur_pull] (zeroed) [push_runs][pull_keys][staging][dest]
    char* p = (char*)d_ws;
    int* cur_push = (int*)p;                  p += (size_t)NB * CPAD * 4;
    int* cur_pull = (int*)p;                  p += (size_t)NB * CPAD * 4;
    size_t zero_bytes = (size_t)(p - (char*)d_ws);
    u64*   push_runs = (u64*)p;               p += (size_t)NB * CAP * 8;
    int*   pull_keys = (int*)p;               p += (size_t)NB * CAP * 4;
    float* staging   = (float*)p;             p += (size_t)NB * CAP * 4;
    int*   dest      = (int*)p;               p += (size_t)n_pull * 4;

    hipMemsetAsync(d_ws, 0, zero_bytes, stream);   // 64KB only

    int gp = (n_push + CHUNK - 1) / CHUNK;
    int gl = (n_pull + CHUNK - 1) / CHUNK;
    scatter_kernel<<<gp + gl, BLK, 0, stream>>>(
        push_idx, n_push, gp, pull_idx, n_pull,
        cur_push, cur_pull, push_runs, pull_keys, dest);
    match_kernel<<<NB, MBLK, 0, stream>>>(push_runs, pull_keys,
                                          cur_push, cur_pull, x, emb, staging);
    unpermute_kernel<<<(n_pull + BLK * 4 - 1) / (BLK * 4), BLK, 0, stream>>>(
        dest, staging, out, n_pull);
}

// Round 13
// 210.285 us; speedup vs baseline: 1.2712x; 1.0813x over previous
//
#include <hip/hip_runtime.h>
#include <stdint.h>

// ---------------------------------------------------------------------------
// HistoryEmbTable: emb.at[push_idx].set(x) then gather emb[pull_idx].
// Last push (highest i) wins on duplicate push indices.
//
// Partition pipeline (best-of rounds 7-13):
//   bucket = key>>17 (512 buckets, 512KB emb window each)
//   K1: FUSED LDS-staged 512-bin scatter (round-11 win): first gp blocks bin
//       push_idx chunks -> u64 (key|pos) runs; remaining blocks bin pull_idx
//       chunks -> int key runs + dest[j]=slot. LDS-atomic ranking,
//       bin-contiguous copy-out, ~512 global cursor atomics/block.
//   K2: match, round-13: LDS cut 144KB -> 48KB so 2 WG/CU (32 waves/CU, HW
//       max; round-11 measured 37.7% occupancy at 1 WG/CU and match was the
//       dominant ~140us). Three phases per bucket:
//         p1: 16KB bloom of THIS bucket's pull keys (LDS atomicOr, stream);
//         p2: insert only pushes passing the pull-bloom (~12%: 6.5% true
//             pushed&pulled + 5.8% FP) into a 4096-slot (32KB) table ->
//             lf ~0.23, probe's first read conclusive-empty 77%;
//         p3: batch-4 probe: emb[key] in flight (chain-break), direct table
//             probe (no push-bloom needed at this lf), coalesced float4
//             staging write (round-11 lesson: NO scattered writes here).
//       Bloom has no false negatives -> exact; last-write-wins via atomicMax.
//   K3: unpermute out[j] = staging[dest[j]] (coalesced dest read, L3-served
//       staging gather, coalesced out write).
// Winner = max push pos (order-free); each j reads its own staging slot, so
// output is deterministic despite nondeterministic scatter order.
// ---------------------------------------------------------------------------

typedef unsigned long long u64;
typedef unsigned u32;

#define NB     512              // buckets
#define BSHIFT 17               // bucket = key >> 17 (keys < 2^26)
#define BLK    256
#define MBLK   1024             // match block: 16 waves; 2 WG/CU via 48KB LDS
#define MB     4                // match batch (items/thread/iter)
#define VPT    16
#define CHUNK  (BLK * VPT)      // 4096 items per scatter block
#define CAP    12288            // per-bucket run capacity (mean 7812, +50 sigma)
#define CPAD   16               // ints per cursor (64B line)
#define TSLOTS 4096             // LDS hash slots (32KB), lf ~0.23
#define TMASK  (TSLOTS - 1)
#define BBITS  131072           // pull-bloom bits (2^17) = 16KB
#define BWORDS (BBITS / 32)
#define BMASK  (BBITS - 1)

__device__ __forceinline__ u32 hkey(int key) { return (u32)key * 2654435761u; }

// ---- K1: fused LDS-binned scatter into 512 bucket runs (push + pull) ----
__global__ __launch_bounds__(BLK)
void scatter_kernel(const int* __restrict__ push_idx, int n_push, int gp,
                    const int* __restrict__ pull_idx, int n_pull,
                    int* __restrict__ cur_push, int* __restrict__ cur_pull,
                    u64* __restrict__ push_runs,
                    int* __restrict__ pull_keys, int* __restrict__ dest) {
    const bool is_push = (int)blockIdx.x < gp;
    const int* __restrict__ idx = is_push ? push_idx : pull_idx;
    const int n   = is_push ? n_push : n_pull;
    const int cid = is_push ? blockIdx.x : blockIdx.x - gp;
    int* __restrict__ cursors = is_push ? cur_push : cur_pull;

    __shared__ u64 buf[CHUNK];          // 32KB
    __shared__ int cnt[NB];             // 2KB
    __shared__ int basel[NB];           // 2KB
    __shared__ int baseg[NB];           // 2KB
    __shared__ int scan[NB];            // 2KB
    int t = threadIdx.x;
    for (int b = t; b < NB; b += BLK) cnt[b] = 0;
    __syncthreads();

    int base = cid * CHUNK;
    int   key_r[VPT];
    short bin_r[VPT];                   // < 512
    short pos_r[VPT];                   // < 4096
    #pragma unroll
    for (int e = 0; e < VPT; ++e) {
        int i = base + e * BLK + t;     // coalesced index load
        if (i < n) {
            int key = idx[i];
            int b = key >> BSHIFT;
            key_r[e] = key;
            bin_r[e] = (short)b;
            pos_r[e] = (short)atomicAdd(&cnt[b], 1);   // LDS atomic (cheap)
        } else bin_r[e] = -1;
    }
    __syncthreads();

    // exclusive scan of cnt -> basel (Hillis-Steele, 2 elems/thread)
    scan[t] = cnt[t]; scan[t + BLK] = cnt[t + BLK];
    __syncthreads();
    for (int d = 1; d < NB; d <<= 1) {
        int a0 = (t       >= d) ? scan[t       - d] : 0;
        int a1 = (t + BLK >= d) ? scan[t + BLK - d] : 0;
        __syncthreads();
        scan[t] += a0; scan[t + BLK] += a1;
        __syncthreads();
    }
    basel[t]       = scan[t]       - cnt[t];
    basel[t + BLK] = scan[t + BLK] - cnt[t + BLK];
    __syncthreads();

    // reserve global run space: ~512 global atomics per block (not 4096)
    for (int b = t; b < NB; b += BLK)
        if (cnt[b] > 0) baseg[b] = atomicAdd(&cursors[b * CPAD], cnt[b]);

    // stage items into LDS, bin-grouped
    #pragma unroll
    for (int e = 0; e < VPT; ++e) {
        if (bin_r[e] >= 0) {
            int i = base + e * BLK + t;
            buf[basel[bin_r[e]] + pos_r[e]] =
                ((u64)(u32)key_r[e] << 32) | (u32)i;    // key | original index
        }
    }
    __syncthreads();

    // copy out: consecutive threads -> consecutive buf slots -> bin-contiguous
    int total = scan[NB - 1];
    for (int q = t; q < total; q += BLK) {
        u64 packed = buf[q];
        int key = (int)(packed >> 32);
        int b = key >> BSHIFT;
        int r = baseg[b] + (q - basel[b]);
        if (r < CAP) {                                  // overflow guard (P~0)
            int gpos = b * CAP + r;
            if (is_push) {
                push_runs[gpos] = packed;               // key | push pos
            } else {
                pull_keys[gpos] = key;
                dest[(u32)packed] = gpos;               // dest[j] = staging slot
            }
        }
    }
}

// ---- K2: per-bucket pull-bloom-filtered LDS match -> coalesced staging ----
__global__ __launch_bounds__(MBLK)
void match_kernel(const u64* __restrict__ push_runs,
                  const int* __restrict__ pull_keys,
                  const int* __restrict__ cur_push,
                  const int* __restrict__ cur_pull,
                  const float* __restrict__ x,
                  const float* __restrict__ emb,
                  float* __restrict__ staging) {
    __shared__ u32 bloom[BWORDS];   // 16KB: pulled-key bloom
    __shared__ u64 tbl[TSLOTS];     // 32KB: filtered push table (lf ~0.23)
    int b = blockIdx.x;
    int np = cur_push[b * CPAD]; np = np < CAP ? np : CAP;
    int nl = cur_pull[b * CPAD]; nl = nl < CAP ? nl : CAP;
    for (int i = threadIdx.x; i < BWORDS; i += MBLK) bloom[i] = 0u;
    for (int i = threadIdx.x; i < TSLOTS; i += MBLK) tbl[i] = 0ull;
    __syncthreads();

    // phase 1: bloom of this bucket's pull keys
    const int* lkeys = pull_keys + (size_t)b * CAP;
    for (int i = threadIdx.x; i < nl; i += MBLK) {
        u32 h = hkey(lkeys[i]);
        atomicOr(&bloom[(h & BMASK) >> 5], 1u << (h & 31));
    }
    __syncthreads();

    // phase 2: insert only pushes whose key might be pulled (~12%)
    const u64* prun = push_runs + (size_t)b * CAP;
    for (int i = threadIdx.x; i < np; i += MBLK) {
        u64 packed = prun[i];
        int key = (int)(packed >> 32);
        u32 h = hkey(key);
        if (!((bloom[(h & BMASK) >> 5] >> (h & 31)) & 1u)) continue;
        u32 key1 = (u32)key + 1u;
        u64 want = ((u64)key1 << 32) | ((u32)packed + 1u);   // (key+1)|(pos+1)
        u32 s = (h >> 20) & TMASK;
        for (;;) {
            u64 prev = atomicCAS(&tbl[s], 0ull, want);
            if (prev == 0ull) break;                          // claimed
            if ((prev >> 32) == key1) { atomicMax(&tbl[s], want); break; }
            s = (s + 1) & TMASK;
        }
    }
    __syncthreads();

    // phase 3: probe pulls, batch-4: emb loads in flight; first table read is
    // conclusive-empty ~77%; coalesced float4 staging store.
    float* stg = staging + (size_t)b * CAP;
    const int STRIDE = MBLK * MB;                 // 4096
    for (int i = threadIdx.x * MB; i + MB <= nl; i += STRIDE) {
        int4 kk = *(const int4*)(lkeys + i);
        int k[MB] = {kk.x, kk.y, kk.z, kk.w};
        float g[MB];
        #pragma unroll
        for (int e = 0; e < MB; ++e) g[e] = emb[k[e]];        // 4 in flight
        u32 h[MB]; u64 tv[MB];
        #pragma unroll
        for (int e = 0; e < MB; ++e) h[e] = hkey(k[e]);
        #pragma unroll
        for (int e = 0; e < MB; ++e) tv[e] = tbl[(h[e] >> 20) & TMASK];
        float r[MB];
        #pragma unroll
        for (int e = 0; e < MB; ++e) {
            float v = g[e];
            u64 cur = tv[e];
            u32 key1 = (u32)k[e] + 1u;
            u32 s = (h[e] >> 20) & TMASK;
            while (cur != 0ull) {                             // walk (rare)
                if ((cur >> 32) == key1) { v = x[(u32)cur - 1u]; break; }
                s = (s + 1) & TMASK;
                cur = tbl[s];
            }
            r[e] = v;
        }
        *(float4*)(stg + i) = make_float4(r[0], r[1], r[2], r[3]);
    }
    // tail (< MB items at the end)
    int tail = (nl / MB) * MB;
    for (int i = tail + threadIdx.x; i < nl; i += MBLK) {
        int key = lkeys[i];
        float v = emb[key];
        u32 h = hkey(key);
        u32 key1 = (u32)key + 1u;
        u32 s = (h >> 20) & TMASK;
        for (;;) {
            u64 cur = tbl[s];
            if (cur == 0ull) break;
            if ((cur >> 32) == key1) { v = x[(u32)cur - 1u]; break; }
            s = (s + 1) & TMASK;
        }
        stg[i] = v;
    }
}

// ---- K3: unpermute (coalesced dest read, L3 staging gather, coalesced out) ----
__global__ __launch_bounds__(BLK)
void unpermute_kernel(const int* __restrict__ dest,
                      const float* __restrict__ staging,
                      float* __restrict__ out, int n) {
    int j0 = (blockIdx.x * BLK + threadIdx.x) * 4;
    if (j0 + 4 <= n) {
        int4 d = *(const int4*)(dest + j0);
        *(float4*)(out + j0) =
            make_float4(staging[d.x], staging[d.y], staging[d.z], staging[d.w]);
    } else {
        for (int j = j0; j < n; ++j) out[j] = staging[dest[j]];
    }
}

extern "C" void kernel_launch(void* const* d_in, const int* in_sizes, int n_in,
                              void* d_out, int out_size, void* d_ws, size_t ws_size,
                              hipStream_t stream) {
    const float* emb      = (const float*)d_in[0];
    const float* x        = (const float*)d_in[1];
    const int*   push_idx = (const int*)d_in[2];
    const int*   pull_idx = (const int*)d_in[3];
    float* out = (float*)d_out;

    const int n_push = in_sizes[2];
    const int n_pull = in_sizes[3];

    // ws layout: [cur_push][cur_pull] (zeroed) [push_runs][pull_keys][staging][dest]
    char* p = (char*)d_ws;
    int* cur_push = (int*)p;                  p += (size_t)NB * CPAD * 4;
    int* cur_pull = (int*)p;                  p += (size_t)NB * CPAD * 4;
    size_t zero_bytes = (size_t)(p - (char*)d_ws);
    u64*   push_runs = (u64*)p;               p += (size_t)NB * CAP * 8;
    int*   pull_keys = (int*)p;               p += (size_t)NB * CAP * 4;
    float* staging   = (float*)p;             p += (size_t)NB * CAP * 4;
    int*   dest      = (int*)p;               p += (size_t)n_pull * 4;

    hipMemsetAsync(d_ws, 0, zero_bytes, stream);   // 64KB only

    int gp = (n_push + CHUNK - 1) / CHUNK;
    int gl = (n_pull + CHUNK - 1) / CHUNK;
    scatter_kernel<<<gp + gl, BLK, 0, stream>>>(
        push_idx, n_push, gp, pull_idx, n_pull,
        cur_push, cur_pull, push_runs, pull_keys, dest);
    match_kernel<<<NB, MBLK, 0, stream>>>(push_runs, pull_keys,
                                          cur_push, cur_pull, x, emb, staging);
    unpermute_kernel<<<(n_pull + BLK * 4 - 1) / (BLK * 4), BLK, 0, stream>>>(
        dest, staging, out, n_pull);
}